// Round 11
// baseline (769.976 us; speedup 1.0000x reference)
//
#include <hip/hip_runtime.h>
#include <hip/hip_bf16.h>
#include <stdint.h>

typedef __attribute__((ext_vector_type(8))) short short8_t;   // 8 x bf16 (4 VGPRs)
typedef __attribute__((ext_vector_type(4))) float f32x4;      // MFMA accum / nt vec

__device__ __forceinline__ unsigned short f2bf(float f) {
  union { float f; unsigned int u; } a;
  a.f = f;
  unsigned int u = a.u;
  u += 0x7fffu + ((u >> 16) & 1u);   // round-to-nearest-even
  return (unsigned short)(u >> 16);
}

__device__ __forceinline__ void gload_lds16(const void* g, void* l) {
  __builtin_amdgcn_global_load_lds(
      (const __attribute__((address_space(1))) void*)g,
      (__attribute__((address_space(3))) void*)l, 16, 0, 0);
}

// ---------------- LayerNorm: fp32 -> bf16 normed rows ----------------
constexpr int D_IN = 4096;

__global__ __launch_bounds__(256) void ln_bf16_kernel(
    const float* __restrict__ x, const float* __restrict__ lnw,
    const float* __restrict__ lnb, unsigned short* __restrict__ out) {
  const int row = blockIdx.x;
  const int tid = threadIdx.x;
  const float* xr = x + (size_t)row * D_IN;

  f32x4 v[4];
  float sum = 0.f, sq = 0.f;
#pragma unroll
  for (int i = 0; i < 4; ++i) {
    v[i] = __builtin_nontemporal_load(
        reinterpret_cast<const f32x4*>(xr + i * 1024 + tid * 4));
    sum += v[i][0] + v[i][1] + v[i][2] + v[i][3];
    sq += v[i][0]*v[i][0] + v[i][1]*v[i][1] + v[i][2]*v[i][2] + v[i][3]*v[i][3];
  }
#pragma unroll
  for (int off = 32; off > 0; off >>= 1) {
    sum += __shfl_down(sum, off, 64);
    sq  += __shfl_down(sq, off, 64);
  }
  __shared__ float s_sum[4], s_sq[4];
  if ((tid & 63) == 0) { s_sum[tid >> 6] = sum; s_sq[tid >> 6] = sq; }
  __syncthreads();
  const float fs = s_sum[0] + s_sum[1] + s_sum[2] + s_sum[3];
  const float fq = s_sq[0] + s_sq[1] + s_sq[2] + s_sq[3];
  const float mean = fs * (1.f / D_IN);
  const float var = fq * (1.f / D_IN) - mean * mean;
  const float rstd = rsqrtf(var + 1e-5f);

  unsigned short* orow = out + (size_t)row * D_IN;
#pragma unroll
  for (int i = 0; i < 4; ++i) {
    const int col = i * 1024 + tid * 4;
    const f32x4 w = *reinterpret_cast<const f32x4*>(lnw + col);
    const f32x4 b = *reinterpret_cast<const f32x4*>(lnb + col);
    ushort4 o;
    o.x = f2bf((v[i][0] - mean) * rstd * w[0] + b[0]);
    o.y = f2bf((v[i][1] - mean) * rstd * w[1] + b[1]);
    o.z = f2bf((v[i][2] - mean) * rstd * w[2] + b[2]);
    o.w = f2bf((v[i][3] - mean) * rstd * w[3] + b[3]);
    *reinterpret_cast<ushort4*>(orow + col) = o;
  }
}

// ---------------- Weight cast fp32 -> bf16 ----------------
__global__ __launch_bounds__(256) void f32_to_bf16_kernel(
    const float* __restrict__ in, unsigned short* __restrict__ out) {
  const size_t i = ((size_t)blockIdx.x * 256 + threadIdx.x) * 8;
  const f32x4 a = __builtin_nontemporal_load(reinterpret_cast<const f32x4*>(in + i));
  const f32x4 b = __builtin_nontemporal_load(reinterpret_cast<const f32x4*>(in + i + 4));
  ushort4 lo, hi;
  lo.x = f2bf(a[0]); lo.y = f2bf(a[1]); lo.z = f2bf(a[2]); lo.w = f2bf(a[3]);
  hi.x = f2bf(b[0]); hi.y = f2bf(b[1]); hi.z = f2bf(b[2]); hi.w = f2bf(b[3]);
  *reinterpret_cast<ushort4*>(out + i) = lo;
  *reinterpret_cast<ushort4*>(out + i + 4) = hi;
}

// ---------------- 256x256 bf16 GEMM: X/Y regions, 2 barriers/ktile ------
// C = A(MxK) * B(NxK)^T + bias.  8 waves (2M x 4N), BK=64, per-ktile loop.
// LDS: A slot0/1 @ 0/32K, B slot0/1 @ 64K/96K.  16x16x32 MFMA (r6 layout).
// Swizzle byte ^= ((row&7)<<4): verified 0 conflicts.  Read addr =
// laneBase[kk] + imm only.
// SCHEDULE (r10 race fixed): per ktile k, slot s=k&1:
//   X(k): 24 ds_reads slot_s + 2 MFMA_Q; lgkmcnt(0); barrier
//         -> certifies ALL waves done reading slot_s (stage-WAR gate)
//   Y(k): 8 stages slot_s <- ktile k+2 + 2 MFMA_Q; vmcnt(8); barrier
//         -> drains ktile k+1's 8 loads (counted, never 0 in steady state)
// Stage depth ~1.5 regions of latency cover. 2 barriers/ktile vs 8-phase's 8.

#define RDA(S, KK, ROW) \
  (*reinterpret_cast<const short8_t*>(((KK) ? aB1 : aB0) + (S)*32768 + (ROW)*128))
#define RDB(S, KK, ROW) \
  (*reinterpret_cast<const short8_t*>(((KK) ? bB1 : bB0) + (S)*32768 + (ROW)*128))

#define READ_A(S, MH)                                          \
  _Pragma("unroll") for (int m_ = 0; m_ < 4; ++m_) {           \
    af[m_][0] = RDA(S, 0, (MH)*64 + m_*16);                    \
    af[m_][1] = RDA(S, 1, (MH)*64 + m_*16);                    \
  }

#define READ_B(S, NH)                                          \
  _Pragma("unroll") for (int n_ = 0; n_ < 2; ++n_) {           \
    bfr[(NH)*2+n_][0] = RDB(S, 0, ((NH)*2+n_)*16);             \
    bfr[(NH)*2+n_][1] = RDB(S, 1, ((NH)*2+n_)*16);             \
  }

#define MFMA_Q(MH, NH)                                                         \
  _Pragma("unroll") for (int kk_ = 0; kk_ < 2; ++kk_) {                        \
    _Pragma("unroll") for (int m_ = 0; m_ < 4; ++m_) {                         \
      _Pragma("unroll") for (int n_ = 0; n_ < 2; ++n_)                         \
        acc[(MH)*4+m_][(NH)*2+n_] = __builtin_amdgcn_mfma_f32_16x16x32_bf16(   \
            af[m_][kk_], bfr[(NH)*2+n_][kk_], acc[(MH)*4+m_][(NH)*2+n_], 0, 0, 0); \
    }                                                                          \
  }

#define STAGE_A(S, U, KT) \
  gload_lds16(aSrc + (size_t)((U)*64) * K + (size_t)(KT)*64, ldsAw + (S)*32768 + (U)*8192)
#define STAGE_B(S, U, KT) \
  gload_lds16(bSrc + (size_t)((U)*64) * K + (size_t)(KT)*64, ldsBw + (S)*32768 + (U)*8192)
#define STAGE_ALL(S, KT)                                       \
  STAGE_A(S,0,KT); STAGE_A(S,1,KT); STAGE_A(S,2,KT); STAGE_A(S,3,KT); \
  STAGE_B(S,0,KT); STAGE_B(S,1,KT); STAGE_B(S,2,KT); STAGE_B(S,3,KT);

// X region: reads + first-half MFMAs, then stage-WAR gate
#define XREG(S)                                                \
  READ_A(S, 0) READ_B(S, 0)                                    \
  __builtin_amdgcn_s_setprio(1);                               \
  MFMA_Q(0,0)                                                  \
  READ_B(S, 1)                                                 \
  MFMA_Q(0,1)                                                  \
  READ_A(S, 1)                                                 \
  __builtin_amdgcn_s_setprio(0);                               \
  asm volatile("s_waitcnt lgkmcnt(0)" ::: "memory");           \
  __builtin_amdgcn_s_barrier();                                \
  asm volatile("" ::: "memory");

// Y region: stage refill + second-half MFMAs, counted-vmcnt gate
#define YREG(S, KT)                                            \
  STAGE_ALL(S, KT)                                             \
  __builtin_amdgcn_s_setprio(1);                               \
  MFMA_Q(1,0)                                                  \
  MFMA_Q(1,1)                                                  \
  __builtin_amdgcn_s_setprio(0);                               \
  asm volatile("s_waitcnt vmcnt(8)" ::: "memory");             \
  __builtin_amdgcn_s_barrier();                                \
  asm volatile("" ::: "memory");

__global__ __launch_bounds__(512, 2) void gemm_xy(
    const unsigned short* __restrict__ A,   // M x K bf16
    const unsigned short* __restrict__ B,   // N x K bf16
    const float* __restrict__ bias,         // N fp32
    float* __restrict__ C,                  // M x N fp32
    int M, int N, int K, int NYB, int BXP) {
  extern __shared__ char smem[];
  const int tid = threadIdx.x;
  const int lane = tid & 63;
  const int wid = tid >> 6;
  const int wr = wid >> 2, wc = wid & 3;
  const int fr = lane & 15;
  const int q16 = (lane >> 4) * 16;
  const int wr128 = wr * 128;
  const int wc64 = wc * 64;

  // XCD mapping: XCD x owns bx in [x*BXP, (x+1)*BXP)
  const int id = blockIdx.x;
  const int xcd = id & 7;
  const int slot = id >> 3;
  const int by = slot % NYB;
  const int bx = xcd * BXP + slot / NYB;
  const int m0 = by * 256, n0 = bx * 256;

  // inverse-swizzled global source for linear global_load_lds dest
  const int s_log = (tid * 16) ^ (((tid >> 3) & 7) << 4);
  const int rsw = s_log >> 7;
  const int csw = (s_log & 127) >> 1;
  const unsigned short* aSrc = A + (size_t)(m0 + rsw) * K + csw;
  const unsigned short* bSrc = B + (size_t)(n0 + rsw) * K + csw;

  char* const ldsAw = smem + wid * 1024;           // wave-uniform stage bases
  char* const ldsBw = smem + 65536 + wid * 1024;

  // 4 lane-base pointers: all fragment reads are base + compile-time offset
  const int s7 = (fr & 7) << 4;
  const char* const aB0 = smem + (wr128 + fr) * 128 + (q16 ^ s7);
  const char* const aB1 = smem + (wr128 + fr) * 128 + ((64 + q16) ^ s7);
  const char* const bB0 = smem + 65536 + (wc64 + fr) * 128 + (q16 ^ s7);
  const char* const bB1 = smem + 65536 + (wc64 + fr) * 128 + ((64 + q16) ^ s7);

  f32x4 acc[8][4] = {};
  short8_t af[4][2], bfr[4][2];

  // ---- prologue: ktile0 -> slot0, ktile1 -> slot1 (8 units each) ----
  STAGE_ALL(0, 0)
  STAGE_ALL(1, 1)
  asm volatile("s_waitcnt vmcnt(8)" ::: "memory");   // ktile0 landed
  __builtin_amdgcn_s_barrier();
  asm volatile("" ::: "memory");

  const int NK = K >> 6;   // ktiles of BK=64 (even; >= 4)
  for (int t = 0; t < (NK - 2) >> 1; ++t) {
    const int k2 = 2*t + 2, k3 = 2*t + 3;
    XREG(0) YREG(0, k2)      // ktile 2t   (slot0), refill slot0 <- ktile 2t+2
    XREG(1) YREG(1, k3)      // ktile 2t+1 (slot1), refill slot1 <- ktile 2t+3
  }
  // ---- tail: ktiles NK-2 (slot0), NK-1 (slot1); no more staging ----
  {
    READ_A(0, 0) READ_B(0, 0)
    __builtin_amdgcn_s_setprio(1);
    MFMA_Q(0,0)
    READ_B(0, 1)
    MFMA_Q(0,1)
    READ_A(0, 1)
    MFMA_Q(1,0)
    MFMA_Q(1,1)
    __builtin_amdgcn_s_setprio(0);
    asm volatile("s_waitcnt lgkmcnt(0)\n\ts_waitcnt vmcnt(0)" ::: "memory");
    __builtin_amdgcn_s_barrier();    // ktile NK-1 landed & published
    asm volatile("" ::: "memory");
    READ_A(1, 0) READ_B(1, 0)
    __builtin_amdgcn_s_setprio(1);
    MFMA_Q(0,0)
    READ_B(1, 1)
    MFMA_Q(0,1)
    READ_A(1, 1)
    MFMA_Q(1,0)
    MFMA_Q(1,1)
    __builtin_amdgcn_s_setprio(0);
  }

  // ---- epilogue: LDS-transpose -> fully-contiguous 1KB nt stores ----
  __syncthreads();   // all waves' K-loop LDS reads done before overwrite
  float* const buf0 = (float*)smem;
  float* const buf1 = (float*)smem + 64 * 260;
  const int cr = (lane >> 4) * 4;
  float bv[4];
#pragma unroll
  for (int ni = 0; ni < 4; ++ni) bv[ni] = bias[n0 + wc64 + ni * 16 + fr];

#pragma unroll
  for (int half = 0; half < 2; ++half) {
    float* const wbuf = (wr == 0) ? buf0 : buf1;
#pragma unroll
    for (int mi4 = 0; mi4 < 4; ++mi4) {
      const int mi = half * 4 + mi4;
#pragma unroll
      for (int j = 0; j < 4; ++j) {
        const int lr = mi4 * 16 + cr + j;   // local row 0..63
#pragma unroll
        for (int ni = 0; ni < 4; ++ni)
          wbuf[lr * 260 + wc64 + ni * 16 + fr] = acc[mi][ni][j] + bv[ni];
      }
    }
    __syncthreads();
#pragma unroll
    for (int i = 0; i < 16; ++i) {
      const int idx = wid * 16 + i;   // 0..127, wave-uniform buffer choice
      const float* src = (idx < 64 ? buf0 + idx * 260 : buf1 + (idx - 64) * 260) + lane * 4;
      const int grow = m0 + (idx < 64 ? half * 64 + idx : 128 + half * 64 + (idx - 64));
      const f32x4 vv = *reinterpret_cast<const f32x4*>(src);
      __builtin_nontemporal_store(
          vv, reinterpret_cast<f32x4*>(C + (size_t)grow * N + n0) + lane);
    }
    __syncthreads();
  }
}

extern "C" void kernel_launch(void* const* d_in, const int* in_sizes, int n_in,
                              void* d_out, int out_size, void* d_ws, size_t ws_size,
                              hipStream_t stream) {
  const float* x    = (const float*)d_in[0];
  const float* w    = (const float*)d_in[1];
  const float* bias = (const float*)d_in[2];
  const float* lnw  = (const float*)d_in[3];
  const float* lnb  = (const float*)d_in[4];
  float* out = (float*)d_out;

  const int DIN  = 4096;
  const int M    = in_sizes[0] / DIN;      // 8192
  const int DOUT = in_sizes[2];            // 12288

  unsigned short* normA = (unsigned short*)d_ws;                 // M x DIN bf16
  unsigned short* wB    = normA + (size_t)M * DIN;               // DOUT x DIN bf16

  ln_bf16_kernel<<<M, 256, 0, stream>>>(x, lnw, lnb, normA);
  f32_to_bf16_kernel<<<((size_t)DOUT * DIN) / (256 * 8), 256, 0, stream>>>(w, wB);

  const int nwg = (M / 256) * (DOUT / 256);   // 1536
  const int smem_bytes = 2 * 64 * 260 * 4 > 131072 ? 2 * 64 * 260 * 4 : 131072; // 133120
  (void)hipFuncSetAttribute((const void*)gemm_xy,
                            hipFuncAttributeMaxDynamicSharedMemorySize, 163840);
  gemm_xy<<<nwg, 512, smem_bytes, stream>>>(normA, wB, bias, out,
                                            M, DOUT, DIN, M / 256, (DOUT / 256) / 8);
}

// Round 12
// 729.464 us; speedup vs baseline: 1.0555x; 1.0555x over previous
//
#include <hip/hip_runtime.h>
#include <hip/hip_bf16.h>
#include <stdint.h>

typedef __attribute__((ext_vector_type(8))) short short8_t;   // 8 x bf16 (4 VGPRs)
typedef __attribute__((ext_vector_type(4))) float f32x4;      // MFMA accum / nt vec

__device__ __forceinline__ unsigned short f2bf(float f) {
  union { float f; unsigned int u; } a;
  a.f = f;
  unsigned int u = a.u;
  u += 0x7fffu + ((u >> 16) & 1u);   // round-to-nearest-even
  return (unsigned short)(u >> 16);
}

__device__ __forceinline__ void gload_lds16(const void* g, void* l) {
  __builtin_amdgcn_global_load_lds(
      (const __attribute__((address_space(1))) void*)g,
      (__attribute__((address_space(3))) void*)l, 16, 0, 0);
}

// ---------------- LayerNorm: fp32 -> bf16 normed rows ----------------
constexpr int D_IN = 4096;

__global__ __launch_bounds__(256) void ln_bf16_kernel(
    const float* __restrict__ x, const float* __restrict__ lnw,
    const float* __restrict__ lnb, unsigned short* __restrict__ out) {
  const int row = blockIdx.x;
  const int tid = threadIdx.x;
  const float* xr = x + (size_t)row * D_IN;

  f32x4 v[4];
  float sum = 0.f, sq = 0.f;
#pragma unroll
  for (int i = 0; i < 4; ++i) {
    v[i] = __builtin_nontemporal_load(
        reinterpret_cast<const f32x4*>(xr + i * 1024 + tid * 4));
    sum += v[i][0] + v[i][1] + v[i][2] + v[i][3];
    sq += v[i][0]*v[i][0] + v[i][1]*v[i][1] + v[i][2]*v[i][2] + v[i][3]*v[i][3];
  }
#pragma unroll
  for (int off = 32; off > 0; off >>= 1) {
    sum += __shfl_down(sum, off, 64);
    sq  += __shfl_down(sq, off, 64);
  }
  __shared__ float s_sum[4], s_sq[4];
  if ((tid & 63) == 0) { s_sum[tid >> 6] = sum; s_sq[tid >> 6] = sq; }
  __syncthreads();
  const float fs = s_sum[0] + s_sum[1] + s_sum[2] + s_sum[3];
  const float fq = s_sq[0] + s_sq[1] + s_sq[2] + s_sq[3];
  const float mean = fs * (1.f / D_IN);
  const float var = fq * (1.f / D_IN) - mean * mean;
  const float rstd = rsqrtf(var + 1e-5f);

  unsigned short* orow = out + (size_t)row * D_IN;
#pragma unroll
  for (int i = 0; i < 4; ++i) {
    const int col = i * 1024 + tid * 4;
    const f32x4 w = *reinterpret_cast<const f32x4*>(lnw + col);
    const f32x4 b = *reinterpret_cast<const f32x4*>(lnb + col);
    ushort4 o;
    o.x = f2bf((v[i][0] - mean) * rstd * w[0] + b[0]);
    o.y = f2bf((v[i][1] - mean) * rstd * w[1] + b[1]);
    o.z = f2bf((v[i][2] - mean) * rstd * w[2] + b[2]);
    o.w = f2bf((v[i][3] - mean) * rstd * w[3] + b[3]);
    *reinterpret_cast<ushort4*>(orow + col) = o;
  }
}

// ---------------- Weight cast fp32 -> bf16 ----------------
__global__ __launch_bounds__(256) void f32_to_bf16_kernel(
    const float* __restrict__ in, unsigned short* __restrict__ out) {
  const size_t i = ((size_t)blockIdx.x * 256 + threadIdx.x) * 8;
  const f32x4 a = __builtin_nontemporal_load(reinterpret_cast<const f32x4*>(in + i));
  const f32x4 b = __builtin_nontemporal_load(reinterpret_cast<const f32x4*>(in + i + 4));
  ushort4 lo, hi;
  lo.x = f2bf(a[0]); lo.y = f2bf(a[1]); lo.z = f2bf(a[2]); lo.w = f2bf(a[3]);
  hi.x = f2bf(b[0]); hi.y = f2bf(b[1]); hi.z = f2bf(b[2]); hi.w = f2bf(b[3]);
  *reinterpret_cast<ushort4*>(out + i) = lo;
  *reinterpret_cast<ushort4*>(out + i + 4) = hi;
}

// ---------------- 256x256 bf16 GEMM: X/Y regions + super-tiled mapping ------
// C = A(MxK) * B(NxK)^T + bias.  8 waves (2M x 4N), BK=64, per-ktile loop.
// LDS: A slot0/1 @ 0/32K, B slot0/1 @ 64K/96K.  16x16x32 MFMA.
// Swizzle byte ^= ((row&7)<<4): verified 0 conflicts.
// Schedule = r11 X/Y (2 barriers/ktile, counted vmcnt(8)).
// SINGLE CHANGE vs r11: block->tile mapping. r11's map gave each XCD's 32
// concurrent blocks 32 distinct A panels (64MB/round through L3; FETCH=1.6GB,
// 10x input ideal). New map: per XCD the concurrent window is an 8(by)x4(bx)
// super-tile -> per round A = 8 panels (16MB, SAME panels on all XCDs) +
// B = 4 panels/XCD. ~2.7x less L3 traffic, A set L3-persistent.
// s=id>>3; g=s/(8*BXP); j=s%(8*BXP); by=g*8+(j&7); bx=xcd*BXP+(j>>3).

#define RDA(S, KK, ROW) \
  (*reinterpret_cast<const short8_t*>(((KK) ? aB1 : aB0) + (S)*32768 + (ROW)*128))
#define RDB(S, KK, ROW) \
  (*reinterpret_cast<const short8_t*>(((KK) ? bB1 : bB0) + (S)*32768 + (ROW)*128))

#define READ_A(S, MH)                                          \
  _Pragma("unroll") for (int m_ = 0; m_ < 4; ++m_) {           \
    af[m_][0] = RDA(S, 0, (MH)*64 + m_*16);                    \
    af[m_][1] = RDA(S, 1, (MH)*64 + m_*16);                    \
  }

#define READ_B(S, NH)                                          \
  _Pragma("unroll") for (int n_ = 0; n_ < 2; ++n_) {           \
    bfr[(NH)*2+n_][0] = RDB(S, 0, ((NH)*2+n_)*16);             \
    bfr[(NH)*2+n_][1] = RDB(S, 1, ((NH)*2+n_)*16);             \
  }

#define MFMA_Q(MH, NH)                                                         \
  _Pragma("unroll") for (int kk_ = 0; kk_ < 2; ++kk_) {                        \
    _Pragma("unroll") for (int m_ = 0; m_ < 4; ++m_) {                         \
      _Pragma("unroll") for (int n_ = 0; n_ < 2; ++n_)                         \
        acc[(MH)*4+m_][(NH)*2+n_] = __builtin_amdgcn_mfma_f32_16x16x32_bf16(   \
            af[m_][kk_], bfr[(NH)*2+n_][kk_], acc[(MH)*4+m_][(NH)*2+n_], 0, 0, 0); \
    }                                                                          \
  }

#define STAGE_A(S, U, KT) \
  gload_lds16(aSrc + (size_t)((U)*64) * K + (size_t)(KT)*64, ldsAw + (S)*32768 + (U)*8192)
#define STAGE_B(S, U, KT) \
  gload_lds16(bSrc + (size_t)((U)*64) * K + (size_t)(KT)*64, ldsBw + (S)*32768 + (U)*8192)
#define STAGE_ALL(S, KT)                                       \
  STAGE_A(S,0,KT); STAGE_A(S,1,KT); STAGE_A(S,2,KT); STAGE_A(S,3,KT); \
  STAGE_B(S,0,KT); STAGE_B(S,1,KT); STAGE_B(S,2,KT); STAGE_B(S,3,KT);

// X region: reads + first-half MFMAs, then stage-WAR gate
#define XREG(S)                                                \
  READ_A(S, 0) READ_B(S, 0)                                    \
  __builtin_amdgcn_s_setprio(1);                               \
  MFMA_Q(0,0)                                                  \
  READ_B(S, 1)                                                 \
  MFMA_Q(0,1)                                                  \
  READ_A(S, 1)                                                 \
  __builtin_amdgcn_s_setprio(0);                               \
  asm volatile("s_waitcnt lgkmcnt(0)" ::: "memory");           \
  __builtin_amdgcn_s_barrier();                                \
  asm volatile("" ::: "memory");

// Y region: stage refill + second-half MFMAs, counted-vmcnt gate
#define YREG(S, KT)                                            \
  STAGE_ALL(S, KT)                                             \
  __builtin_amdgcn_s_setprio(1);                               \
  MFMA_Q(1,0)                                                  \
  MFMA_Q(1,1)                                                  \
  __builtin_amdgcn_s_setprio(0);                               \
  asm volatile("s_waitcnt vmcnt(8)" ::: "memory");             \
  __builtin_amdgcn_s_barrier();                                \
  asm volatile("" ::: "memory");

__global__ __launch_bounds__(512, 2) void gemm_xy(
    const unsigned short* __restrict__ A,   // M x K bf16
    const unsigned short* __restrict__ B,   // N x K bf16
    const float* __restrict__ bias,         // N fp32
    float* __restrict__ C,                  // M x N fp32
    int M, int N, int K, int NYB, int BXP) {
  extern __shared__ char smem[];
  const int tid = threadIdx.x;
  const int lane = tid & 63;
  const int wid = tid >> 6;
  const int wr = wid >> 2, wc = wid & 3;
  const int fr = lane & 15;
  const int q16 = (lane >> 4) * 16;
  const int wr128 = wr * 128;
  const int wc64 = wc * 64;

  // Super-tiled XCD mapping: concurrent window per XCD = 8(by) x BXP/..4(bx)
  const int id = blockIdx.x;
  const int xcd = id & 7;
  const int s = id >> 3;                 // 0 .. NYB*BXP-1
  const int gsz = 8 * BXP;               // blocks per by-group per XCD
  const int g = s / gsz;
  const int j = s - g * gsz;
  const int by = g * 8 + (j & 7);
  const int bx = xcd * BXP + (j >> 3);
  const int m0 = by * 256, n0 = bx * 256;

  // inverse-swizzled global source for linear global_load_lds dest
  const int s_log = (tid * 16) ^ (((tid >> 3) & 7) << 4);
  const int rsw = s_log >> 7;
  const int csw = (s_log & 127) >> 1;
  const unsigned short* aSrc = A + (size_t)(m0 + rsw) * K + csw;
  const unsigned short* bSrc = B + (size_t)(n0 + rsw) * K + csw;

  char* const ldsAw = smem + wid * 1024;           // wave-uniform stage bases
  char* const ldsBw = smem + 65536 + wid * 1024;

  // 4 lane-base pointers: all fragment reads are base + compile-time offset
  const int s7 = (fr & 7) << 4;
  const char* const aB0 = smem + (wr128 + fr) * 128 + (q16 ^ s7);
  const char* const aB1 = smem + (wr128 + fr) * 128 + ((64 + q16) ^ s7);
  const char* const bB0 = smem + 65536 + (wc64 + fr) * 128 + (q16 ^ s7);
  const char* const bB1 = smem + 65536 + (wc64 + fr) * 128 + ((64 + q16) ^ s7);

  f32x4 acc[8][4] = {};
  short8_t af[4][2], bfr[4][2];

  // ---- prologue: ktile0 -> slot0, ktile1 -> slot1 (8 units each) ----
  STAGE_ALL(0, 0)
  STAGE_ALL(1, 1)
  asm volatile("s_waitcnt vmcnt(8)" ::: "memory");   // ktile0 landed
  __builtin_amdgcn_s_barrier();
  asm volatile("" ::: "memory");

  const int NK = K >> 6;   // ktiles of BK=64 (even; >= 4)
  for (int t = 0; t < (NK - 2) >> 1; ++t) {
    const int k2 = 2*t + 2, k3 = 2*t + 3;
    XREG(0) YREG(0, k2)      // ktile 2t   (slot0), refill slot0 <- ktile 2t+2
    XREG(1) YREG(1, k3)      // ktile 2t+1 (slot1), refill slot1 <- ktile 2t+3
  }
  // ---- tail: ktiles NK-2 (slot0), NK-1 (slot1); no more staging ----
  {
    READ_A(0, 0) READ_B(0, 0)
    __builtin_amdgcn_s_setprio(1);
    MFMA_Q(0,0)
    READ_B(0, 1)
    MFMA_Q(0,1)
    READ_A(0, 1)
    MFMA_Q(1,0)
    MFMA_Q(1,1)
    __builtin_amdgcn_s_setprio(0);
    asm volatile("s_waitcnt lgkmcnt(0)\n\ts_waitcnt vmcnt(0)" ::: "memory");
    __builtin_amdgcn_s_barrier();    // ktile NK-1 landed & published
    asm volatile("" ::: "memory");
    READ_A(1, 0) READ_B(1, 0)
    __builtin_amdgcn_s_setprio(1);
    MFMA_Q(0,0)
    READ_B(1, 1)
    MFMA_Q(0,1)
    READ_A(1, 1)
    MFMA_Q(1,0)
    MFMA_Q(1,1)
    __builtin_amdgcn_s_setprio(0);
  }

  // ---- epilogue: LDS-transpose -> fully-contiguous 1KB nt stores ----
  __syncthreads();   // all waves' K-loop LDS reads done before overwrite
  float* const buf0 = (float*)smem;
  float* const buf1 = (float*)smem + 64 * 260;
  const int cr = (lane >> 4) * 4;
  float bv[4];
#pragma unroll
  for (int ni = 0; ni < 4; ++ni) bv[ni] = bias[n0 + wc64 + ni * 16 + fr];

#pragma unroll
  for (int half = 0; half < 2; ++half) {
    float* const wbuf = (wr == 0) ? buf0 : buf1;
#pragma unroll
    for (int mi4 = 0; mi4 < 4; ++mi4) {
      const int mi = half * 4 + mi4;
#pragma unroll
      for (int j2 = 0; j2 < 4; ++j2) {
        const int lr = mi4 * 16 + cr + j2;   // local row 0..63
#pragma unroll
        for (int ni = 0; ni < 4; ++ni)
          wbuf[lr * 260 + wc64 + ni * 16 + fr] = acc[mi][ni][j2] + bv[ni];
      }
    }
    __syncthreads();
#pragma unroll
    for (int i = 0; i < 16; ++i) {
      const int idx = wid * 16 + i;   // 0..127, wave-uniform buffer choice
      const float* src = (idx < 64 ? buf0 + idx * 260 : buf1 + (idx - 64) * 260) + lane * 4;
      const int grow = m0 + (idx < 64 ? half * 64 + idx : 128 + half * 64 + (idx - 64));
      const f32x4 vv = *reinterpret_cast<const f32x4*>(src);
      __builtin_nontemporal_store(
          vv, reinterpret_cast<f32x4*>(C + (size_t)grow * N + n0) + lane);
    }
    __syncthreads();
  }
}

extern "C" void kernel_launch(void* const* d_in, const int* in_sizes, int n_in,
                              void* d_out, int out_size, void* d_ws, size_t ws_size,
                              hipStream_t stream) {
  const float* x    = (const float*)d_in[0];
  const float* w    = (const float*)d_in[1];
  const float* bias = (const float*)d_in[2];
  const float* lnw  = (const float*)d_in[3];
  const float* lnb  = (const float*)d_in[4];
  float* out = (float*)d_out;

  const int DIN  = 4096;
  const int M    = in_sizes[0] / DIN;      // 8192
  const int DOUT = in_sizes[2];            // 12288

  unsigned short* normA = (unsigned short*)d_ws;                 // M x DIN bf16
  unsigned short* wB    = normA + (size_t)M * DIN;               // DOUT x DIN bf16

  ln_bf16_kernel<<<M, 256, 0, stream>>>(x, lnw, lnb, normA);
  f32_to_bf16_kernel<<<((size_t)DOUT * DIN) / (256 * 8), 256, 0, stream>>>(w, wB);

  const int nwg = (M / 256) * (DOUT / 256);   // 1536
  const int smem_bytes = 2 * 64 * 260 * 4 > 131072 ? 2 * 64 * 260 * 4 : 131072; // 133120
  (void)hipFuncSetAttribute((const void*)gemm_xy,
                            hipFuncAttributeMaxDynamicSharedMemorySize, 163840);
  gemm_xy<<<nwg, 512, smem_bytes, stream>>>(normA, wB, bias, out,
                                            M, DOUT, DIN, M / 256, (DOUT / 256) / 8);
}